// Round 1
// 79.530 us; speedup vs baseline: 1.0048x; 1.0048x over previous
//
#include <hip/hip_runtime.h>

namespace {
constexpr int N   = 64;
constexpr int D   = 32;
constexpr int PD  = 36;   // padded ind row (dwords): measured conflict-free (r1/r2)
constexpr int SHP = 72;   // sh row pad: >=64 payload; 72%32==8 same conflict-free
                          // residue as the measured 104 (r11-r14). Shrinks LDS to
                          // 46848 B -> 2 blocks/CU with grid 512 = EXACT capacity.
constexpr float LOG2E = 1.4426950408889634f;
constexpr float LN2   = 0.6931471805599453f;

typedef float f32x2 __attribute__((ext_vector_type(2)));

#if __has_builtin(__builtin_amdgcn_exp2f)
__device__ __forceinline__ float fexp2(float x) { return __builtin_amdgcn_exp2f(x); }
#else
__device__ __forceinline__ float fexp2(float x) { return exp2f(x); }
#endif
#if __has_builtin(__builtin_amdgcn_rcpf)
__device__ __forceinline__ float frcp(float x) { return __builtin_amdgcn_rcpf(x); }
#else
__device__ __forceinline__ float frcp(float x) { return 1.0f / x; }
#endif
__device__ __forceinline__ void wavebar() {
#if __has_builtin(__builtin_amdgcn_wave_barrier)
    __builtin_amdgcn_wave_barrier();
#endif
}

// r17: WHOLE-b BLOCKS. Grid 512 (1 block per b), block 512 (8 waves), 8 i-rows
// per wave. Fixes the r16 structural occupancy bug: LDS 41728 B allowed only
// 3 blocks/CU resident against a 4-blocks/CU grid (1024) -> lockstep phase-1 +
// a 256-block tail at 8 waves/CU. Now LDS 46848 B -> 2 blocks/CU and grid 512
// = exactly 2/CU: zero tail, and ind staging / s[a][n] / feature reads / gate
// are computed ONCE per b instead of twice.
// Gate: w-row (ind1[lane]) hoisted to VGPRs once -> the r-loop is pure
// s_load+VALU, one lgkmcnt batch per row (SMEM returns are unordered; mixing
// ds_read with s_load forces lgkmcnt(0) drains - r16 lesson extended).
// Score math unchanged from r14/r16 (verified): single-exp identity
//   elup1(a)*elup1(b) = exp2(min(aL,0)+min(bL,0)) * (1+max(aL,0)*ln2) * (1+max(bL,0)*ln2)
// with sign-split on wave-uniform s0 (s_cmp branch) and v-rows via scalar pipe.
__global__ __launch_bounds__(512, 4) void fused(
        const float* __restrict__ feature,
        const float* __restrict__ ind,
        float* __restrict__ out) {
    __shared__ float ind_lds[3][N][PD];   // 27648 B
    __shared__ float s_lds[3][N];         //   768 B
    __shared__ float sh_lds[N][SHP];      // 18432 B   total 46848 B -> 2 blocks/CU

    const int t    = threadIdx.x;
    const int lane = t & 63;
    const int wave = t >> 6;
    const int b    = blockIdx.x;

    // ---- stage indicator: 1536 float4, 3 per thread, coalesced ----
    {
        const float4* src = reinterpret_cast<const float4*>(ind);
#pragma unroll
        for (int idx = t; idx < 3 * N * D / 4; idx += 512) {
            int a = idx >> 9;
            int r = idx & 511;
            int n = r >> 3;
            int k = r & 7;
            *reinterpret_cast<float4*>(&ind_lds[a][n][k * 4]) = src[idx];
        }
    }

    // ---- s[a][n] = feature[b,n,:] . ind[a,n,:] from GLOBAL, overlapped with
    //      staging (single barrier; r13-verified). Now once per b. ----
    if (t < 3 * N) {
        int a = t >> 6, n = t & 63;
        const float4* frow = reinterpret_cast<const float4*>(feature + ((size_t)b * N + n) * D);
        const float4* irow = reinterpret_cast<const float4*>(ind + (a * N + n) * D);
        f32x2 sa2 = {0.f, 0.f};
#pragma unroll
        for (int k = 0; k < 8; ++k) {
            float4 f4 = frow[k];
            float4 i4 = irow[k];
            sa2 = __builtin_elementwise_fma(f32x2{f4.x, f4.y}, f32x2{i4.x, i4.y}, sa2);
            sa2 = __builtin_elementwise_fma(f32x2{f4.z, f4.w}, f32x2{i4.z, i4.w}, sa2);
        }
        s_lds[a][n] = sa2.x + sa2.y;
    }
    __syncthreads();   // the ONLY block barrier

    // wave-uniform row indices (readfirstlane -> SGPR -> s_load addresses)
    int igu[8];
#pragma unroll
    for (int r = 0; r < 8; ++r)
        igu[r] = __builtin_amdgcn_readfirstlane(wave * 8 + r);

    // ---- gate bitmasks: w-row in VGPRs (8 ds_read_b128, one batch), then
    //      r-loop with a-rows via SCALAR loads (one lgkmcnt batch per row) ----
    unsigned long long gmask[8];
    {
        f32x2 wv[16];
#pragma unroll
        for (int k4 = 0; k4 < 8; ++k4) {
            float4 w4 = *reinterpret_cast<const float4*>(&ind_lds[1][lane][k4 * 4]);
            wv[k4 * 2 + 0] = f32x2{w4.x, w4.y};
            wv[k4 * 2 + 1] = f32x2{w4.z, w4.w};
        }
#pragma unroll
        for (int r = 0; r < 8; ++r) {
            f32x2 ga = {0.f, 0.f};
#pragma unroll
            for (int k4 = 0; k4 < 8; ++k4) {
                float4 a4 = *reinterpret_cast<const float4*>(ind + igu[r] * D + k4 * 4);  // s_load
                ga = __builtin_elementwise_fma(f32x2{a4.x, a4.y}, wv[k4 * 2 + 0], ga);
                ga = __builtin_elementwise_fma(f32x2{a4.z, a4.w}, wv[k4 * 2 + 1], ga);
            }
            gmask[r] = __ballot(ga.x + ga.y > 0.f);
        }
    }

    const float s1Ls = s_lds[1][lane] * LOG2E;
    const f32x2 s1L  = {s1Ls, s1Ls};
    const f32x2 ln2v = {LN2, LN2};
    const f32x2 onev = {1.0f, 1.0f};
    const f32x2 zerv = {0.0f, 0.0f};

    // ---- hoisted row scalars ----
    float s0v[8];
#pragma unroll
    for (int r = 0; r < 8; ++r) s0v[r] = s_lds[0][wave * 8 + r] * LOG2E;

    // ---- score: sign-split packed loop, 2 chunks of 16 d-elements;
    //      v4 rows via SCALAR loads from global ind1 (wave-uniform addr) ----
    f32x2 sc2[8] = {{0.f, 0.f}, {0.f, 0.f}, {0.f, 0.f}, {0.f, 0.f},
                    {0.f, 0.f}, {0.f, 0.f}, {0.f, 0.f}, {0.f, 0.f}};

#define SCORE_BODY(NEGA, FMAA, AM, FM)                                              \
    {                                                                               \
        const f32x2 amv = {(AM), (AM)};                                             \
        const f32x2 fmv = {(FM), (FM)};                                             \
        f32x2 acc = sc2[r];                                                         \
        _Pragma("unroll")                                                           \
        for (int k4 = 0; k4 < 4; ++k4) {                                            \
            float4 v4 = *reinterpret_cast<const float4*>(                           \
                ind + N * D + igu[r] * D + c * 16 + k4 * 4);   /* s_load */         \
            f32x2 vp[2] = {f32x2{v4.x, v4.y}, f32x2{v4.z, v4.w}};                   \
            _Pragma("unroll")                                                       \
            for (int h = 0; h < 2; ++h) {                                           \
                f32x2 aneg = amv * NEGA[k4 * 2 + h];                                \
                f32x2 A    = __builtin_elementwise_fma(fmv, FMAA[k4 * 2 + h], onev);\
                f32x2 bL   = s1L * vp[h];                                           \
                f32x2 bneg = __builtin_elementwise_min(bL, zerv);                   \
                f32x2 B    = __builtin_elementwise_fma(                             \
                    __builtin_elementwise_max(bL, zerv), ln2v, onev);               \
                f32x2 mn   = aneg + bneg;                                           \
                f32x2 E    = {fexp2(mn.x), fexp2(mn.y)};                            \
                acc = __builtin_elementwise_fma(E * A, B, acc);                     \
            }                                                                       \
        }                                                                           \
        sc2[r] = acc;                                                               \
    }

#pragma unroll
    for (int c = 0; c < 2; ++c) {
        // per-chunk precompute: un = min(u,0), upl = max(u,0)*ln2  (16 f32x2 live)
        f32x2 un[8], upl[8];
#pragma unroll
        for (int k4 = 0; k4 < 4; ++k4) {
            float4 v = *reinterpret_cast<const float4*>(&ind_lds[0][lane][c * 16 + k4 * 4]);
            f32x2 x0 = {v.x, v.y}, x1 = {v.z, v.w};
            f32x2 n0 = __builtin_elementwise_min(x0, zerv);
            f32x2 n1 = __builtin_elementwise_min(x1, zerv);
            un[k4 * 2 + 0]  = n0;
            un[k4 * 2 + 1]  = n1;
            upl[k4 * 2 + 0] = (x0 - n0) * ln2v;
            upl[k4 * 2 + 1] = (x1 - n1) * ln2v;
        }
#pragma unroll
        for (int r = 0; r < 8; ++r) {
            // force wave-uniform scalar: s_cmp + s_cbranch, zero divergence
            const float s0u = __uint_as_float(
                __builtin_amdgcn_readfirstlane(__float_as_uint(s0v[r])));
            if (s0u >= 0.f) {
                SCORE_BODY(un, upl, s0u, s0u)
            } else {
                SCORE_BODY(upl, un, s0u * LOG2E, s0u * LN2)
            }
        }
    }
#undef SCORE_BODY

    float score[8];
#pragma unroll
    for (int r = 0; r < 8; ++r) score[r] = sc2[r].x + sc2[r].y;

    // ---- 8-way-ILP wave softmax over j (64 lanes) ----
    float mx[8], e[8], sm[8];
#pragma unroll
    for (int r = 0; r < 8; ++r) mx[r] = score[r];
#pragma unroll
    for (int off = 32; off >= 1; off >>= 1) {
#pragma unroll
        for (int r = 0; r < 8; ++r) mx[r] = fmaxf(mx[r], __shfl_xor(mx[r], off));
    }
#pragma unroll
    for (int r = 0; r < 8; ++r) e[r] = fexp2((score[r] - mx[r]) * LOG2E);
#pragma unroll
    for (int r = 0; r < 8; ++r) sm[r] = e[r];
#pragma unroll
    for (int off = 32; off >= 1; off >>= 1) {
#pragma unroll
        for (int r = 0; r < 8; ++r) sm[r] += __shfl_xor(sm[r], off);
    }
#pragma unroll
    for (int r = 0; r < 8; ++r) {
        const int ig  = wave * 8 + r;
        const float g = (float)((gmask[r] >> lane) & 1ull);
        sh_lds[ig][lane] = (e[r] * g) * (s_lds[2][ig] * frcp(sm[r]));
    }

    // NO block barrier: wave w wrote sh rows 8w..8w+7 and phase 2's thread t
    // (row t>>3) reads only those rows (same-wave LDS RAW, lgkmcnt-ordered;
    // r13/r14-verified pattern).
    wavebar();

    // ---- phase 2: out[i,:] = sh[i,:] @ ind2; thread = (i_loc, d-quad) ----
    // 8 threads per row, full 64-j loop, no jh split / no shuffle combine.
    // sh4: broadcast within 8-lane group, 2-way across groups (free, m136).
    // ind2 quad: 8 dq x 4 dwords = 32 consecutive banks, rows broadcast.
    {
        const int i_loc = t >> 3;
        const int dq    = t & 7;
        f32x2 acc0 = {0.f, 0.f}, acc1 = {0.f, 0.f};
#pragma unroll
        for (int j = 0; j < 64; j += 4) {
            float4 sh4 = *reinterpret_cast<const float4*>(&sh_lds[i_loc][j]);
#pragma unroll
            for (int c = 0; c < 4; ++c) {
                float4 v4 = *reinterpret_cast<const float4*>(&ind_lds[2][j + c][dq * 4]);
                float  w  = (&sh4.x)[c];
                f32x2 wvv = {w, w};
                acc0 = __builtin_elementwise_fma(wvv, f32x2{v4.x, v4.y}, acc0);
                acc1 = __builtin_elementwise_fma(wvv, f32x2{v4.z, v4.w}, acc1);
            }
        }
        float4 acc = {acc0.x, acc0.y, acc1.x, acc1.y};
        *reinterpret_cast<float4*>(out + ((size_t)b * N + i_loc) * D + dq * 4) = acc;
    }
}
}  // namespace

extern "C" void kernel_launch(void* const* d_in, const int* in_sizes, int n_in,
                              void* d_out, int out_size, void* d_ws, size_t ws_size,
                              hipStream_t stream) {
    const float* feature = (const float*)d_in[0];
    const float* ind     = (const float*)d_in[1];
    float*       out     = (float*)d_out;
    fused<<<512, 512, 0, stream>>>(feature, ind, out);
}